// Round 17
// baseline (126.830 us; speedup 1.0000x reference)
//
#include <hip/hip_runtime.h>
#include <math.h>

// Sizes (fixed by the problem)
#define B_ 8
#define C_ 64
#define T_ 16
#define H_ 56
#define W_ 56
#define HW_ (H_ * W_)   // 3136
#define CR_ 16
#define PLANE (T_ * HW_)   // 50176 floats per (b,c) plane

typedef __attribute__((ext_vector_type(8))) short bf16x8;
typedef __attribute__((ext_vector_type(4))) float f32x4;

// ---------------- helpers ----------------
__device__ __forceinline__ unsigned short f2bf(float f) {
    unsigned u = __float_as_uint(f);
    u += 0x7fffu + ((u >> 16) & 1u);   // round to nearest even
    return (unsigned short)(u >> 16);
}

__device__ __forceinline__ void gload_lds16(const void* g, void* l) {
    __builtin_amdgcn_global_load_lds(
        (const __attribute__((address_space(1))) unsigned int*)g,
        (__attribute__((address_space(3))) unsigned int*)l,
        16, 0, 0);
}

// raw barrier with lgkm-only drain (keeps DMA pipeline alive across it)
#define BAR_LGKM() do { \
    asm volatile("s_waitcnt lgkmcnt(0)" ::: "memory"); \
    __builtin_amdgcn_sched_barrier(0); \
    __builtin_amdgcn_s_barrier(); \
    __builtin_amdgcn_sched_barrier(0); } while (0)

// ---------------- K1: pool (+fused prepack) ------------------------------
// Blocks < 8192: xt[b,c,t] = sum over HW of x (pure linear float4 read).
// Blocks >= 8192 (288 blocks x 128 thr): pack Wconv -> bf16 MFMA A-frags.
__global__ __launch_bounds__(128) void pool_prepack_kernel(
    const float* __restrict__ x, const float* __restrict__ Wconv,
    float* __restrict__ xt, unsigned short* __restrict__ packWbf)
{
    int blk = blockIdx.x;
    int tid = threadIdx.x;
    if (blk >= 8192) {
        int idx = (blk - 8192) * 128 + tid;    // 0..36863
        if (idx < 64 * 576) {
            int j     = idx & 7;
            int lane  = (idx >> 3) & 63;
            int mt    = (idx >> 9) & 3;
            int kstep = idx >> 11;             // 0..17
            int cih = kstep & 1, tap = kstep >> 1;
            int co = mt * 16 + (lane & 15);
            int ci = cih * 32 + (lane >> 4) * 8 + j;
            packWbf[idx] = f2bf(Wconv[(co * C_ + ci) * 9 + tap]);
        }
        return;
    }
    __shared__ float red[2];
    const float4* p = (const float4*)(x + (size_t)blk * HW_);
    float s = 0.f;
    #pragma unroll
    for (int k = 0; k < 7; ++k) {
        int i = tid + k * 128;
        if (i < 784) { float4 v = p[i]; s += (v.x + v.y) + (v.z + v.w); }
    }
    #pragma unroll
    for (int off = 32; off > 0; off >>= 1) s += __shfl_down(s, off);
    if ((tid & 63) == 0) red[tid >> 6] = s;
    __syncthreads();
    if (tid == 0) xt[blk] = red[0] + red[1];
}

// ---------------- K2: conv (T3/T4 counted-vmcnt DMA pipeline) ------------
// r11 compute structure (256 thr = 4 waves, wave = 7nt x 4mt, acc[7][4]).
// Staging: 8 groups of 8 planes; fbuf double-buffered; groups g,g+1 always
// in flight; raw barriers with vmcnt(6) (0 only at last group) -- never
// drain the DMA queue mid-loop. Uniform DMA shape: every block reads 10
// full rows from row0=clamp(h0-1,0,46); edge strips use a uniform row
// shift d and zero-predicate instead of variable byte counts.
#define LCOLS2 58
#define HROWE (4 * LCOLS2)          // 232 bf16x8 per stored row (half)

__device__ __forceinline__ void issue_grp(const float* xb, float* dstbuf,
                                          int g, int row0, int wv, int lane)
{
    #pragma unroll
    for (int pj = 0; pj < 2; ++pj) {
        int j = wv * 2 + pj;
        const char* src = (const char*)(xb + (size_t)(g * 8 + j) * PLANE
                                        + (size_t)row0 * W_);
        float* dst = dstbuf + j * 560;
        gload_lds16(src + lane * 16, dst);                       // seg0 (64 ln)
        gload_lds16(src + 1024 + lane * 16, dst + 256);          // seg1 (64 ln)
        if (lane < 12)
            gload_lds16(src + 2048 + lane * 16, dst + 512);      // seg2 (12 ln)
    }   // 6 gload_lds per wave per group, always (uniform vmcnt accounting)
}

__global__ __launch_bounds__(256) void conv_mfma_kernel(
    const float* __restrict__ x, const float* __restrict__ emb,
    const int* __restrict__ viewp, const float* __restrict__ xt,
    const float* __restrict__ Wg, const float* __restrict__ bg,
    const float* __restrict__ Wa, const float* __restrict__ ba,
    const float* __restrict__ bng, const float* __restrict__ bnb,
    const float* __restrict__ bnm, const float* __restrict__ bnv,
    const float* __restrict__ Wb,
    const unsigned short* __restrict__ packWbf, float* __restrict__ part)
{
    __shared__ bf16x8 ltile[10 * HROWE];    // 37120 B (prologue scratch alias)
    __shared__ float fbuf[2][8 * 560];      // 2 x 17920 B: f32 DMA dbuf
    __shared__ float sa[C_], sea[C_];
    __shared__ float smax[4][C_];

    int blk = blockIdx.x;                   // natural order (r12 lesson)
    int strip = blk % 7;
    int bt = blk / 7;
    int b = bt >> 4, t = bt & 15;
    int h0 = strip * 8;
    int tid = threadIdx.x;
    int lane = tid & 63, wv = tid >> 6;
    int q4 = lane >> 4, li = lane & 15;

    int row0 = h0 - 1; if (row0 < 0) row0 = 0; if (row0 > 46) row0 = 46;
    int d    = (h0 == 0) ? -1 : ((h0 == 48) ? 1 : 0);   // fbuf row shift

    const float* xb = x + ((size_t)(b * C_) * T_ + t) * HW_;   // + ci*PLANE

    // ---- prefetch groups 0,1 (in flight under the whole prologue) ----
    issue_grp(xb, fbuf[0], 0, row0, wv, lane);
    issue_grp(xb, fbuf[1], 1, row0, wv, lane);

    // ======== route prologue (scratch aliased onto ltile) ========
    float* scr = (float*)ltile;
    float* z   = scr;            // [64][18], slot = t+1; slots 0,17 = zero pad
    float* swa = scr + 1152;     // Wa staged: [i][r*3+tap], stride 49
    float* hsv = scr + 4288;     // h[r*3+s], s = tap slot (t-1+s)
    float* ggv = scr + 4352;     // gg[64]
    float* gsv = scr + 4416;     // gs[64]

    {   // P0: z = xt/HW + emb ; stage Wa (all reads coalesced)
        int view = viewp[0];
        for (int i = tid; i < 1024; i += 256) {
            int c = i >> 4, tt = i & 15;
            z[c * 18 + tt + 1] = xt[b * 1024 + i] * (1.f / HW_) + emb[view * C_ + c];
        }
        if (tid < 128) { int c = tid & 63; z[c * 18 + (tid < 64 ? 0 : 17)] = 0.f; }
        for (int i = tid; i < 3072; i += 256) {
            float v = Wa[i];
            int r = i / 192, rem = i - r * 192;
            int ii = rem / 3, tap = rem - ii * 3;
            swa[ii * 49 + r * 3 + tap] = v;
        }
    }
    BAR_LGKM();
    if (tid < 64) {   // P1: gs = mean over t
        float s = 0.f;
        #pragma unroll
        for (int k = 1; k <= 16; ++k) s += z[tid * 18 + k];
        gsv[tid] = s * (1.f / 16.f);
    }
    BAR_LGKM();
    {   // P2: gg = Wg.gs + bg (coalesced row trick)
        float p = 0.f;
        const float* wrow = Wg + tid * 16;
        int q = tid & 3;
        #pragma unroll
        for (int k = 0; k < 16; ++k) p = fmaf(wrow[k], gsv[q * 16 + k], p);
        p += __shfl_xor(p, 1);
        p += __shfl_xor(p, 2);
        if (q == 0) ggv[tid >> 2] = p + bg[tid >> 2];
    }
    BAR_LGKM();
    for (int i = tid; i < 1024; i += 256) {   // P3: z += gg (interior only)
        int c = i >> 4, tt = i & 15;
        z[c * 18 + tt + 1] += ggv[c];
    }
    BAR_LGKM();
    if (tid < 48) {   // P4: h[r][s] for t' = t-1+s (BN + relu; 0 if t' OOB)
        int r = tid & 15, s = tid >> 4;
        int tp = t - 1 + s;
        float hv = 0.f;
        if ((unsigned)tp < 16u) {
            float v = ba[r];
            #pragma unroll 8
            for (int i2 = 0; i2 < 64; ++i2) {
                const float* wa = swa + i2 * 49 + r * 3;
                const float* zr = z + i2 * 18 + tp;    // slots tp, tp+1, tp+2
                v = fmaf(zr[0], wa[0], v);
                v = fmaf(zr[1], wa[1], v);
                v = fmaf(zr[2], wa[2], v);
            }
            v = (v - bnm[r]) * rsqrtf(bnv[r] + 1e-5f);
            v = fmaf(v, bng[r], bnb[r]);
            hv = fmaxf(v, 0.f);
        }
        hsv[r * 3 + s] = hv;
    }
    BAR_LGKM();
    {   // P5: alpha = Wb.h + 1; sa/sea
        float p = 0.f;
        const float* wrow = Wb + tid * 12;
        int q = tid & 3;
        #pragma unroll
        for (int k = 0; k < 12; ++k) p = fmaf(wrow[k], hsv[q * 12 + k], p);
        p += __shfl_xor(p, 1);
        p += __shfl_xor(p, 2);
        if (q == 0) {
            int c = tid >> 2;
            float a = p + 1.f;
            sa[c] = a;
            sea[c] = emb[viewp[0] * C_ + c] * a;
        }
    }
    BAR_LGKM();   // prologue done; ltile free

    // zero border cols 0,57 of ltile (transform never writes them)
    if (tid >= 64 && tid < 144) {
        int i = tid - 64;            // 0..79 = 10 rows x 4 ch x 2 sides
        int r = i / 8, c8 = i - r * 8;
        int ch4 = c8 >> 1, col = (c8 & 1) ? 57 : 0;
        ltile[(r * 4 + ch4) * LCOLS2 + col] = (bf16x8){0,0,0,0,0,0,0,0};
    }

    int baddr[7];
    #pragma unroll
    for (int nt = 0; nt < 7; ++nt) {
        int p = (wv * 7 + nt) * 16 + li;
        int row = p / W_, col = p - row * W_;
        baddr[nt] = row * HROWE + q4 * LCOLS2 + col;
    }

    f32x4 acc[7][4];
    #pragma unroll
    for (int nt = 0; nt < 7; ++nt)
        #pragma unroll
        for (int mt = 0; mt < 4; ++mt)
            acc[nt][mt] = (f32x4){0.f, 0.f, 0.f, 0.f};

    const bf16x8* pw = (const bf16x8*)packWbf;

    // ---- pipelined group loop: g,g+1 always in flight ----
    #pragma unroll
    for (int g = 0; g < 8; ++g) {
        // wait for group g's data (keep g+1's 6 DMAs in flight)
        if (g < 7) { asm volatile("s_waitcnt vmcnt(6)" ::: "memory"); }
        else       { asm volatile("s_waitcnt vmcnt(0)" ::: "memory"); }
        __builtin_amdgcn_sched_barrier(0);
        __builtin_amdgcn_s_barrier();
        __builtin_amdgcn_sched_barrier(0);

        // transform group g: fbuf[g&1] -> ltile (alpha/emb fma + bf16 pack)
        {
            const int half = g >> 2, ch4 = g & 3;
            const float* fb = fbuf[g & 1];
            if (tid < 140) {
                int row = tid / 14, cq = tid - row * 14;
                bool valid = !((h0 == 0 && row == 0) || (h0 == 48 && row == 9));
                int ci0 = half * 32 + ch4 * 8;
                bf16x8 hv[4] = {(bf16x8){0,0,0,0,0,0,0,0}, (bf16x8){0,0,0,0,0,0,0,0},
                                (bf16x8){0,0,0,0,0,0,0,0}, (bf16x8){0,0,0,0,0,0,0,0}};
                if (valid) {
                    int fr = row + d;
                    float4 f[8];
                    #pragma unroll
                    for (int j = 0; j < 8; ++j)
                        f[j] = *(const float4*)&fb[j * 560 + fr * 56 + cq * 4];
                    #pragma unroll
                    for (int j = 0; j < 8; ++j) {
                        float aj = sa[ci0 + j], ej = sea[ci0 + j];
                        hv[0][j] = (short)f2bf(fmaf(f[j].x, aj, ej));
                        hv[1][j] = (short)f2bf(fmaf(f[j].y, aj, ej));
                        hv[2][j] = (short)f2bf(fmaf(f[j].z, aj, ej));
                        hv[3][j] = (short)f2bf(fmaf(f[j].w, aj, ej));
                    }
                }
                bf16x8* dst = &ltile[(row * 4 + ch4) * LCOLS2 + cq * 4 + 1];
                #pragma unroll
                for (int cc = 0; cc < 4; ++cc) dst[cc] = hv[cc];
            }
        }
        BAR_LGKM();   // ltile visible; fbuf[g&1] reads complete -> reusable

        // refill the buffer just freed with group g+2
        if (g + 2 <= 7) issue_grp(xb, fbuf[g & 1], g + 2, row0, wv, lane);

        // after last group of each half: 9 taps of MFMA (DMAs fly beneath)
        if ((g & 3) == 3) {
            const int half = g >> 2;
            #pragma unroll
            for (int tap = 0; tap < 9; ++tap) {
                const int kh = tap / 3, kw = tap % 3;
                const int kstep = tap * 2 + half;
                const int boff = kh * HROWE + kw;
                bf16x8 af[4];
                #pragma unroll
                for (int mt = 0; mt < 4; ++mt)
                    af[mt] = pw[(kstep * 4 + mt) * 64 + lane];
                #pragma unroll
                for (int nt = 0; nt < 7; ++nt) {
                    bf16x8 bfr = ltile[baddr[nt] + boff];
                    #pragma unroll
                    for (int mt = 0; mt < 4; ++mt)
                        acc[nt][mt] = __builtin_amdgcn_mfma_f32_16x16x32_bf16(
                            af[mt], bfr, acc[nt][mt], 0, 0, 0);
                }
            }
        }
    }

    // ---- strip max -> part[blk][cout] (plain coalesced store) ----
    float m[4][4];
    #pragma unroll
    for (int mt = 0; mt < 4; ++mt)
        #pragma unroll
        for (int i = 0; i < 4; ++i) {
            float v = acc[0][mt][i];
            #pragma unroll
            for (int nt = 1; nt < 7; ++nt) v = fmaxf(v, acc[nt][mt][i]);
            m[mt][i] = v;
        }
    #pragma unroll
    for (int off = 1; off < 16; off <<= 1)
        #pragma unroll
        for (int mt = 0; mt < 4; ++mt)
            #pragma unroll
            for (int i = 0; i < 4; ++i)
                m[mt][i] = fmaxf(m[mt][i], __shfl_xor(m[mt][i], off));
    if (li == 0) {
        #pragma unroll
        for (int mt = 0; mt < 4; ++mt)
            #pragma unroll
            for (int i = 0; i < 4; ++i)
                smax[wv][mt * 16 + q4 * 4 + i] = m[mt][i];
    }
    __syncthreads();
    if (tid < C_) {
        float mm = fmaxf(fmaxf(smax[0][tid], smax[1][tid]),
                         fmaxf(smax[2][tid], smax[3][tid]));
        part[(size_t)blk * C_ + tid] = mm;
    }
}

// ---------------- K3: reduce part + classifier (fused) ------------------
__global__ __launch_bounds__(512) void cls_kernel(
    const float* __restrict__ part, const float* __restrict__ Wcls,
    const float* __restrict__ bcls, float* __restrict__ out)
{
    __shared__ float pooled[512];
    int tid = threadIdx.x;
    int b = tid >> 6, c = tid & 63;
    const float* pb = part + (size_t)b * 112 * C_ + c;
    float m0 = -INFINITY, m1 = -INFINITY, m2 = -INFINITY, m3 = -INFINITY;
    #pragma unroll
    for (int i = 0; i < 28; ++i) {
        m0 = fmaxf(m0, pb[(i     ) * C_]);
        m1 = fmaxf(m1, pb[(i + 28) * C_]);
        m2 = fmaxf(m2, pb[(i + 56) * C_]);
        m3 = fmaxf(m3, pb[(i + 84) * C_]);
    }
    pooled[tid] = fmaxf(fmaxf(m0, m1), fmaxf(m2, m3));
    __syncthreads();
    if (tid < B_ * 10) {
        int bb = tid / 10, k = tid - (tid / 10) * 10;
        float v = bcls[k];
        #pragma unroll 8
        for (int cc = 0; cc < C_; ++cc)
            v = fmaf(pooled[bb * C_ + cc], Wcls[k * C_ + cc], v);
        out[tid] = v;
    }
}

// ---------------- launcher ----------------
extern "C" void kernel_launch(void* const* d_in, const int* in_sizes, int n_in,
                              void* d_out, int out_size, void* d_ws, size_t ws_size,
                              hipStream_t stream)
{
    const float* x     = (const float*)d_in[0];
    const int*   view  = (const int*)  d_in[1];
    const float* emb   = (const float*)d_in[2];
    const float* Wg    = (const float*)d_in[3];
    const float* bg    = (const float*)d_in[4];
    const float* Wa    = (const float*)d_in[5];
    const float* ba    = (const float*)d_in[6];
    const float* bng   = (const float*)d_in[7];
    const float* bnb   = (const float*)d_in[8];
    const float* bnm   = (const float*)d_in[9];
    const float* bnv   = (const float*)d_in[10];
    const float* Wb    = (const float*)d_in[11];
    const float* Wconv = (const float*)d_in[12];
    const float* Wcls  = (const float*)d_in[13];
    const float* bcls  = (const float*)d_in[14];
    float* out = (float*)d_out;

    char* wsb = (char*)d_ws;
    float*          xt      = (float*)(wsb + 0);               // 32768 B
    float*          part    = (float*)(wsb + 32768);           // 229376 B
    unsigned short* packWbf = (unsigned short*)(wsb + 262144); // 73728 B

    hipLaunchKernelGGL(pool_prepack_kernel, dim3(8192 + 288), dim3(128), 0, stream,
                       x, Wconv, xt, packWbf);
    hipLaunchKernelGGL(conv_mfma_kernel, dim3(B_ * T_ * 7), dim3(256), 0, stream,
                       x, emb, view, xt, Wg, bg, Wa, ba, bng, bnb, bnm, bnv, Wb,
                       packWbf, part);
    hipLaunchKernelGGL(cls_kernel, dim3(1), dim3(512), 0, stream,
                       part, Wcls, bcls, out);
}

// Round 18
// 82.484 us; speedup vs baseline: 1.5376x; 1.5376x over previous
//
#include <hip/hip_runtime.h>
#include <math.h>

// Sizes (fixed by the problem)
#define B_ 8
#define C_ 64
#define T_ 16
#define H_ 56
#define W_ 56
#define HW_ (H_ * W_)   // 3136
#define CR_ 16
#define PLANE (T_ * HW_)   // 50176 floats per (b,c) plane

typedef __attribute__((ext_vector_type(8))) short bf16x8;
typedef __attribute__((ext_vector_type(4))) float f32x4;

// ---------------- helpers ----------------
__device__ __forceinline__ unsigned short f2bf(float f) {
    unsigned u = __float_as_uint(f);
    u += 0x7fffu + ((u >> 16) & 1u);   // round to nearest even
    return (unsigned short)(u >> 16);
}

// ---------------- K1: pool (+fused prepack) ------------------------------
// Blocks < 8192: xt[b,c,t] = sum over HW of x (pure linear float4 read).
// Blocks >= 8192 (288 blocks x 128 thr): pack Wconv -> bf16 MFMA A-frags.
// packWbf element idx = ((kstep*4 + mtile)*64 + lane)*8 + j
//   kstep = tap*2 + cih ; co = mtile*16 + (lane&15)
//   ci = cih*32 + (lane>>4)*8 + j ; tap = kh*3+kw
__global__ __launch_bounds__(128) void pool_prepack_kernel(
    const float* __restrict__ x, const float* __restrict__ Wconv,
    float* __restrict__ xt, unsigned short* __restrict__ packWbf)
{
    int blk = blockIdx.x;
    int tid = threadIdx.x;
    if (blk >= 8192) {
        int idx = (blk - 8192) * 128 + tid;    // 0..36863
        if (idx < 64 * 576) {
            int j     = idx & 7;
            int lane  = (idx >> 3) & 63;
            int mt    = (idx >> 9) & 3;
            int kstep = idx >> 11;             // 0..17
            int cih = kstep & 1, tap = kstep >> 1;
            int co = mt * 16 + (lane & 15);
            int ci = cih * 32 + (lane >> 4) * 8 + j;
            packWbf[idx] = f2bf(Wconv[(co * C_ + ci) * 9 + tap]);
        }
        return;
    }
    __shared__ float red[2];
    const float4* p = (const float4*)(x + (size_t)blk * HW_);
    float s = 0.f;
    #pragma unroll
    for (int k = 0; k < 7; ++k) {
        int i = tid + k * 128;
        if (i < 784) { float4 v = p[i]; s += (v.x + v.y) + (v.z + v.w); }
    }
    #pragma unroll
    for (int off = 32; off > 0; off >>= 1) s += __shfl_down(s, off);
    if ((tid & 63) == 0) red[tid >> 6] = s;
    __syncthreads();
    if (tid == 0) xt[blk] = red[0] + red[1];
}

// ---------------- K2: conv (route prologue + MFMA + strip-max) ----------
// r11 structure verbatim (256 thr = 4 waves, wave = 7nt x 4mt, acc[7][4]).
// ONE change: block order REVERSED (blk = N-1-blockIdx) so conv's first
// reads hit the L3-freshest tail of x left by pool (which streamed x in
// ascending order). Bijective remap of independent blocks; zero risk.
#define LCOLS2 58
#define HROWE (4 * LCOLS2)          // 232 bf16x8 per stored row (half)

__global__ __launch_bounds__(256) void conv_mfma_kernel(
    const float* __restrict__ x, const float* __restrict__ emb,
    const int* __restrict__ viewp, const float* __restrict__ xt,
    const float* __restrict__ Wg, const float* __restrict__ bg,
    const float* __restrict__ Wa, const float* __restrict__ ba,
    const float* __restrict__ bng, const float* __restrict__ bnb,
    const float* __restrict__ bnm, const float* __restrict__ bnv,
    const float* __restrict__ Wb,
    const unsigned short* __restrict__ packWbf, float* __restrict__ part)
{
    __shared__ bf16x8 ltile[10 * HROWE];    // 37120 B (prologue scratch alias)
    __shared__ float sa[C_], sea[C_];
    __shared__ float smax[4][C_];

    int blk = (B_ * T_ * 7 - 1) - blockIdx.x;   // reversed (L3 recency match)
    int strip = blk % 7;
    int bt = blk / 7;
    int b = bt >> 4, t = bt & 15;
    int h0 = strip * 8;
    int tid = threadIdx.x;
    int lane = tid & 63, wv = tid >> 6;
    int q4 = lane >> 4, li = lane & 15;

    // ======== route prologue (scratch aliased onto ltile) ========
    float* scr = (float*)ltile;
    float* z   = scr;            // [64][18], slot = t+1; slots 0,17 = zero pad
    float* swa = scr + 1152;     // Wa staged: [i][r*3+tap], stride 49
    float* hsv = scr + 4288;     // h[r*3+s], s = tap slot (t-1+s)
    float* ggv = scr + 4352;     // gg[64]
    float* gsv = scr + 4416;     // gs[64]

    {   // P0: z = xt/HW + emb ; stage Wa (all reads coalesced)
        int view = viewp[0];
        for (int i = tid; i < 1024; i += 256) {
            int c = i >> 4, tt = i & 15;
            z[c * 18 + tt + 1] = xt[b * 1024 + i] * (1.f / HW_) + emb[view * C_ + c];
        }
        if (tid < 128) { int c = tid & 63; z[c * 18 + (tid < 64 ? 0 : 17)] = 0.f; }
        for (int i = tid; i < 3072; i += 256) {
            float v = Wa[i];
            int r = i / 192, rem = i - r * 192;
            int ii = rem / 3, tap = rem - ii * 3;
            swa[ii * 49 + r * 3 + tap] = v;
        }
    }
    __syncthreads();
    if (tid < 64) {   // P1: gs = mean over t
        float s = 0.f;
        #pragma unroll
        for (int k = 1; k <= 16; ++k) s += z[tid * 18 + k];
        gsv[tid] = s * (1.f / 16.f);
    }
    __syncthreads();
    {   // P2: gg = Wg.gs + bg (coalesced row trick)
        float p = 0.f;
        const float* wrow = Wg + tid * 16;
        int q = tid & 3;
        #pragma unroll
        for (int k = 0; k < 16; ++k) p = fmaf(wrow[k], gsv[q * 16 + k], p);
        p += __shfl_xor(p, 1);
        p += __shfl_xor(p, 2);
        if (q == 0) ggv[tid >> 2] = p + bg[tid >> 2];
    }
    __syncthreads();
    for (int i = tid; i < 1024; i += 256) {   // P3: z += gg (interior only)
        int c = i >> 4, tt = i & 15;
        z[c * 18 + tt + 1] += ggv[c];
    }
    __syncthreads();
    if (tid < 48) {   // P4: h[r][s] for t' = t-1+s (BN + relu; 0 if t' OOB)
        int r = tid & 15, s = tid >> 4;
        int tp = t - 1 + s;
        float hv = 0.f;
        if ((unsigned)tp < 16u) {
            float v = ba[r];
            #pragma unroll 8
            for (int i2 = 0; i2 < 64; ++i2) {
                const float* wa = swa + i2 * 49 + r * 3;
                const float* zr = z + i2 * 18 + tp;    // slots tp, tp+1, tp+2
                v = fmaf(zr[0], wa[0], v);
                v = fmaf(zr[1], wa[1], v);
                v = fmaf(zr[2], wa[2], v);
            }
            v = (v - bnm[r]) * rsqrtf(bnv[r] + 1e-5f);
            v = fmaf(v, bng[r], bnb[r]);
            hv = fmaxf(v, 0.f);
        }
        hsv[r * 3 + s] = hv;
    }
    __syncthreads();
    {   // P5: alpha = Wb.h + 1; sa/sea
        float p = 0.f;
        const float* wrow = Wb + tid * 12;
        int q = tid & 3;
        #pragma unroll
        for (int k = 0; k < 12; ++k) p = fmaf(wrow[k], hsv[q * 12 + k], p);
        p += __shfl_xor(p, 1);
        p += __shfl_xor(p, 2);
        if (q == 0) {
            int c = tid >> 2;
            float a = p + 1.f;
            sa[c] = a;
            sea[c] = emb[viewp[0] * C_ + c] * a;
        }
    }
    __syncthreads();   // prologue done; ltile free for staging

    // zero border cols 0,57 (never touched by interior staging)
    if (tid >= 64 && tid < 144) {
        int i = tid - 64;            // 0..79 = 10 rows x 4 ch x 2 sides
        int r = i / 8, c8 = i - r * 8;
        int ch4 = c8 >> 1, col = (c8 & 1) ? 57 : 0;
        ltile[(r * 4 + ch4) * LCOLS2 + col] = (bf16x8){0,0,0,0,0,0,0,0};
    }

    const float* xb = x + ((size_t)(b * C_) * T_ + t) * HW_;   // + ci*PLANE

    int baddr[7];
    #pragma unroll
    for (int nt = 0; nt < 7; ++nt) {
        int p = (wv * 7 + nt) * 16 + li;
        int row = p / W_, col = p - row * W_;
        baddr[nt] = row * HROWE + q4 * LCOLS2 + col;
    }

    f32x4 acc[7][4];
    #pragma unroll
    for (int nt = 0; nt < 7; ++nt)
        #pragma unroll
        for (int mt = 0; mt < 4; ++mt)
            acc[nt][mt] = (f32x4){0.f, 0.f, 0.f, 0.f};

    const bf16x8* pw = (const bf16x8*)packWbf;

    #pragma unroll
    for (int half = 0; half < 2; ++half) {
        if (half) __syncthreads();   // WAR: MFMA h0 reads done before overwrite
        // ---- stage 560 items (4 ch4 x 10 rows x 14 colquads) from x ----
        #pragma unroll
        for (int k = 0; k < 3; ++k) {
            int item = tid + k * 256;
            if (item < 560) {
                int ch4 = item / 140;
                int rem = item - ch4 * 140;
                int row = rem / 14, cq = rem - row * 14;
                int gr = h0 - 1 + row;
                int ci0 = half * 32 + ch4 * 8;
                bf16x8 hv[4] = {(bf16x8){0,0,0,0,0,0,0,0}, (bf16x8){0,0,0,0,0,0,0,0},
                                (bf16x8){0,0,0,0,0,0,0,0}, (bf16x8){0,0,0,0,0,0,0,0}};
                if ((unsigned)gr < (unsigned)H_) {
                    const float* src = xb + (size_t)ci0 * PLANE + gr * W_ + cq * 4;
                    float4 f[8];
                    #pragma unroll
                    for (int j = 0; j < 8; ++j)
                        f[j] = *(const float4*)(src + (size_t)j * PLANE);
                    #pragma unroll
                    for (int j = 0; j < 8; ++j) {
                        float aj = sa[ci0 + j], ej = sea[ci0 + j];
                        hv[0][j] = (short)f2bf(fmaf(f[j].x, aj, ej));
                        hv[1][j] = (short)f2bf(fmaf(f[j].y, aj, ej));
                        hv[2][j] = (short)f2bf(fmaf(f[j].z, aj, ej));
                        hv[3][j] = (short)f2bf(fmaf(f[j].w, aj, ej));
                    }
                }
                bf16x8* dst = &ltile[(row * 4 + ch4) * LCOLS2 + cq * 4 + 1];
                #pragma unroll
                for (int cc = 0; cc < 4; ++cc) dst[cc] = hv[cc];
            }
        }
        __syncthreads();

        // ---- 9 taps x (4 mt x 7 nt) MFMA on this 32-ci half ----
        #pragma unroll
        for (int tap = 0; tap < 9; ++tap) {
            const int kh = tap / 3, kw = tap % 3;
            const int kstep = tap * 2 + half;
            const int boff = kh * HROWE + kw;
            bf16x8 af[4];
            #pragma unroll
            for (int mt = 0; mt < 4; ++mt)
                af[mt] = pw[(kstep * 4 + mt) * 64 + lane];
            #pragma unroll
            for (int nt = 0; nt < 7; ++nt) {
                bf16x8 bfr = ltile[baddr[nt] + boff];
                #pragma unroll
                for (int mt = 0; mt < 4; ++mt)
                    acc[nt][mt] = __builtin_amdgcn_mfma_f32_16x16x32_bf16(
                        af[mt], bfr, acc[nt][mt], 0, 0, 0);
            }
        }
    }

    // ---- strip max -> part[blk][cout] (plain coalesced store) ----
    float m[4][4];
    #pragma unroll
    for (int mt = 0; mt < 4; ++mt)
        #pragma unroll
        for (int i = 0; i < 4; ++i) {
            float v = acc[0][mt][i];
            #pragma unroll
            for (int nt = 1; nt < 7; ++nt) v = fmaxf(v, acc[nt][mt][i]);
            m[mt][i] = v;
        }
    #pragma unroll
    for (int off = 1; off < 16; off <<= 1)
        #pragma unroll
        for (int mt = 0; mt < 4; ++mt)
            #pragma unroll
            for (int i = 0; i < 4; ++i)
                m[mt][i] = fmaxf(m[mt][i], __shfl_xor(m[mt][i], off));
    if (li == 0) {
        #pragma unroll
        for (int mt = 0; mt < 4; ++mt)
            #pragma unroll
            for (int i = 0; i < 4; ++i)
                smax[wv][mt * 16 + q4 * 4 + i] = m[mt][i];
    }
    __syncthreads();
    if (tid < C_) {
        float mm = fmaxf(fmaxf(smax[0][tid], smax[1][tid]),
                         fmaxf(smax[2][tid], smax[3][tid]));
        part[(size_t)blk * C_ + tid] = mm;
    }
}

// ---------------- K3: reduce part + classifier (fused) ------------------
__global__ __launch_bounds__(512) void cls_kernel(
    const float* __restrict__ part, const float* __restrict__ Wcls,
    const float* __restrict__ bcls, float* __restrict__ out)
{
    __shared__ float pooled[512];
    int tid = threadIdx.x;
    int b = tid >> 6, c = tid & 63;
    const float* pb = part + (size_t)b * 112 * C_ + c;
    float m0 = -INFINITY, m1 = -INFINITY, m2 = -INFINITY, m3 = -INFINITY;
    #pragma unroll
    for (int i = 0; i < 28; ++i) {
        m0 = fmaxf(m0, pb[(i     ) * C_]);
        m1 = fmaxf(m1, pb[(i + 28) * C_]);
        m2 = fmaxf(m2, pb[(i + 56) * C_]);
        m3 = fmaxf(m3, pb[(i + 84) * C_]);
    }
    pooled[tid] = fmaxf(fmaxf(m0, m1), fmaxf(m2, m3));
    __syncthreads();
    if (tid < B_ * 10) {
        int bb = tid / 10, k = tid - (tid / 10) * 10;
        float v = bcls[k];
        #pragma unroll 8
        for (int cc = 0; cc < C_; ++cc)
            v = fmaf(pooled[bb * C_ + cc], Wcls[k * C_ + cc], v);
        out[tid] = v;
    }
}

// ---------------- launcher ----------------
extern "C" void kernel_launch(void* const* d_in, const int* in_sizes, int n_in,
                              void* d_out, int out_size, void* d_ws, size_t ws_size,
                              hipStream_t stream)
{
    const float* x     = (const float*)d_in[0];
    const int*   view  = (const int*)  d_in[1];
    const float* emb   = (const float*)d_in[2];
    const float* Wg    = (const float*)d_in[3];
    const float* bg    = (const float*)d_in[4];
    const float* Wa    = (const float*)d_in[5];
    const float* ba    = (const float*)d_in[6];
    const float* bng   = (const float*)d_in[7];
    const float* bnb   = (const float*)d_in[8];
    const float* bnm   = (const float*)d_in[9];
    const float* bnv   = (const float*)d_in[10];
    const float* Wb    = (const float*)d_in[11];
    const float* Wconv = (const float*)d_in[12];
    const float* Wcls  = (const float*)d_in[13];
    const float* bcls  = (const float*)d_in[14];
    float* out = (float*)d_out;

    char* wsb = (char*)d_ws;
    float*          xt      = (float*)(wsb + 0);               // 32768 B
    float*          part    = (float*)(wsb + 32768);           // 229376 B
    unsigned short* packWbf = (unsigned short*)(wsb + 262144); // 73728 B

    hipLaunchKernelGGL(pool_prepack_kernel, dim3(8192 + 288), dim3(128), 0, stream,
                       x, Wconv, xt, packWbf);
    hipLaunchKernelGGL(conv_mfma_kernel, dim3(B_ * T_ * 7), dim3(256), 0, stream,
                       x, emb, view, xt, Wg, bg, Wa, ba, bng, bnb, bnm, bnv, Wb,
                       packWbf, part);
    hipLaunchKernelGGL(cls_kernel, dim3(1), dim3(512), 0, stream,
                       part, Wcls, bcls, out);
}